// Round 4
// baseline (202.415 us; speedup 1.0000x reference)
//
#include <hip/hip_runtime.h>
#include <math.h>

typedef unsigned short u16;
typedef unsigned int u32;
typedef float f32x4 __attribute__((ext_vector_type(4)));
typedef u32 u32x4 __attribute__((ext_vector_type(4)));

// ---- problem dims: B=2 S=2048 E=1024 H=16 HD=64 ----
static const size_t TAB_B  = 0;         // float2[2048][32]
static const size_t QBF_B  = 524288;    // bf16 [2][16][2048][64], pre-scaled 0.125*log2e
static const size_t KBF_B  = 8912896;   // bf16 [2][16][2048][64]
static const size_t VTB_B  = 17301504;  // bf16 [2][16][64][2048]  (V transposed)
static const size_t W2HI_B = 25690112;  // bf16 [1024][1024]
static const size_t W2LO_B = 27787264;
static const size_t XBF_B  = 29884416;  // bf16 x      (dead after QKV gemm)
static const size_t W1BF_B = 38273024;  // bf16 w1     (dead after QKV gemm)
static const size_t OHI_B  = 29884416;  // bf16 [4096][1024], reuses XBF
static const size_t OLO_B  = 38273024;  // bf16 [4096][1024], reuses W1BF

#if __has_builtin(__builtin_amdgcn_exp2f)
#define EXP2(x) __builtin_amdgcn_exp2f(x)
#else
#define EXP2(x) __expf(0.69314718056f * (x))
#endif

__device__ __forceinline__ u16 f2bf(float f) {
  u32 u = __builtin_bit_cast(u32, f);
  u += 0x7fffu + ((u >> 16) & 1u);
  return (u16)(u >> 16);
}
__device__ __forceinline__ float bf2f(u16 h) {
  return __builtin_bit_cast(float, (u32)h << 16);
}
__device__ __forceinline__ u32 pk2bf(float a, float b) {
  return (u32)f2bf(a) | ((u32)f2bf(b) << 16);  // a low 16, b high 16
}
// inline-asm MFMA: D/C = acc ("+v"), A, B as 4-VGPR tuples of packed bf16.
__device__ __forceinline__ void mfma16(f32x4& d, u32x4 a, u32x4 b) {
  asm volatile("v_mfma_f32_16x16x32_bf16 %0, %1, %2, %0"
               : "+v"(d)
               : "v"(a), "v"(b));
}
// async global->LDS, 16B per lane; lds dest = wave-uniform base (+lane*16 by HW)
__device__ __forceinline__ void gld16(const void* g, void* l) {
  __builtin_amdgcn_global_load_lds(
      (const __attribute__((address_space(1))) void*)(void*)g,
      (__attribute__((address_space(3))) void*)l, 16, 0, 0);
}
// MFMA->VALU read hazard fence (inline-asm MFMAs: compiler can't see latency)
#define HZ() asm volatile("s_nop 7\ns_nop 7\ns_nop 7\ns_nop 7")

// ============================================================================
// prep: rope table + bf16 converts, fused (one launch).
// blocks [0,256): tab; [256,1280): x; [1280,2048): w1; [2048,2304): w2 split
// ============================================================================
__global__ __launch_bounds__(256) void prep_kernel(
    const float* __restrict__ x, const float* __restrict__ w1,
    const float* __restrict__ w2, float2* __restrict__ tab,
    u16* __restrict__ xbf, u16* __restrict__ w1bf, u16* __restrict__ w2hi,
    u16* __restrict__ w2lo) {
  const int blk = blockIdx.x;
  const int t = threadIdx.x;
  if (blk < 256) {
    const int idx = (blk << 8) + t;
    const int s = idx >> 5, i = idx & 31;
    double theta = pow(10000.0, -((double)(2 * i)) / 64.0);
    float ang = (float)s * (float)theta;
    tab[idx] = make_float2(cosf(ang), sinf(ang));
  } else if (blk < 1280) {
    int i = ((blk - 256) << 8) + t;
#pragma unroll
    for (int r = 0; r < 4; ++r, i += 262144) {
      float4 v = ((const float4*)x)[i];
      ushort4 o;
      o.x = f2bf(v.x); o.y = f2bf(v.y); o.z = f2bf(v.z); o.w = f2bf(v.w);
      ((ushort4*)xbf)[i] = o;
    }
  } else if (blk < 2048) {
    int i = ((blk - 1280) << 8) + t;
#pragma unroll
    for (int r = 0; r < 4; ++r, i += 196608) {
      float4 v = ((const float4*)w1)[i];
      ushort4 o;
      o.x = f2bf(v.x); o.y = f2bf(v.y); o.z = f2bf(v.z); o.w = f2bf(v.w);
      ((ushort4*)w1bf)[i] = o;
    }
  } else {
    int i = ((blk - 2048) << 8) + t;
#pragma unroll
    for (int r = 0; r < 4; ++r, i += 65536) {
      float4 v = ((const float4*)w2)[i];
      ushort4 h, l;
      h.x = f2bf(v.x); h.y = f2bf(v.y); h.z = f2bf(v.z); h.w = f2bf(v.w);
      l.x = f2bf(v.x - bf2f(h.x));
      l.y = f2bf(v.y - bf2f(h.y));
      l.z = f2bf(v.z - bf2f(h.z));
      l.w = f2bf(v.w - bf2f(h.w));
      ((ushort4*)w2hi)[i] = h;
      ((ushort4*)w2lo)[i] = l;
    }
  }
}

// ============================================================================
// B^T GEMM: C[m][n] = sum_k A[m][k]*B[n][k], lda=ldb=1024 (bf16), 128x128 tile,
// BK=64, 4 waves (2x2 of 64x64). global_load_lds with XOR-swizzled source.
// MODE 0: 1-pass (nkb=16), epilogue = RoPE + scatter q(scaled)/k/vT bf16.
// MODE 1: 3-pass hi/lo split (nkb=48), epilogue = f32 store to out.
// ============================================================================
template <int MODE>
__global__ __launch_bounds__(256) void gemm_bt(
    const u16* __restrict__ Ahi, const u16* __restrict__ Alo,
    const u16* __restrict__ Bhi, const u16* __restrict__ Blo, int nbn, int nkb,
    const float2* __restrict__ tab, u16* __restrict__ qd, u16* __restrict__ kd,
    u16* __restrict__ vtd, float* __restrict__ fout) {
  __shared__ __align__(16) char As[16384];  // [128 rows][64 k] bf16, swizzled
  __shared__ __align__(16) char Bs[16384];
  const int bm = blockIdx.x / nbn;
  const int bn = blockIdx.x % nbn;
  const int m0 = bm << 7;
  const int n0 = bn << 7;
  const int t = threadIdx.x;
  const int w = t >> 6;
  const int lane = t & 63;
  const int lr = lane & 15;  // A-row / B-col within 16
  const int lg = lane >> 4;  // k-group
  const int wr0 = (w >> 1) << 6;
  const int wc0 = (w & 1) << 6;
  const int srow0 = t >> 3;  // staging row (+32/round)
  const int sblk = t & 7;    // staging 16B-block within 128B row

  f32x4 acc[4][4];
#pragma unroll
  for (int mi = 0; mi < 4; ++mi)
#pragma unroll
    for (int ni = 0; ni < 4; ++ni) acc[mi][ni] = (f32x4)0.0f;

  for (int kb = 0; kb < nkb; ++kb) {
    const int pass = kb >> 4;
    const int k0 = (kb & 15) << 6;
    const u16* Ap = (MODE == 1 && pass == 2) ? Alo : Ahi;
    const u16* Bp = (MODE == 1 && pass == 1) ? Blo : Bhi;
    if (kb) __syncthreads();
#pragma unroll
    for (int r = 0; r < 4; ++r) {
      const int row = srow0 + (r << 5);
      const int g = sblk ^ (row & 7);  // inverse-swizzled source chunk
      gld16(Ap + (size_t)(m0 + row) * 1024 + k0 + (g << 3),
            As + (r << 12) + (w << 10));
      gld16(Bp + (size_t)(n0 + row) * 1024 + k0 + (g << 3),
            Bs + (r << 12) + (w << 10));
    }
    asm volatile("s_waitcnt vmcnt(0)" ::: "memory");
    __syncthreads();
#pragma unroll
    for (int kk = 0; kk < 2; ++kk) {
      u32x4 af[4], bf[4];
#pragma unroll
      for (int mi = 0; mi < 4; ++mi) {
        const int row = wr0 + (mi << 4) + lr;
        af[mi] = *(const u32x4*)(As + row * 128 +
                                 ((((kk << 2) + lg) ^ (row & 7)) << 4));
      }
#pragma unroll
      for (int ni = 0; ni < 4; ++ni) {
        const int row = wc0 + (ni << 4) + lr;
        bf[ni] = *(const u32x4*)(Bs + row * 128 +
                                 ((((kk << 2) + lg) ^ (row & 7)) << 4));
      }
      asm volatile("s_nop 1");
      __builtin_amdgcn_s_setprio(1);
#pragma unroll
      for (int mi = 0; mi < 4; ++mi)
#pragma unroll
        for (int ni = 0; ni < 4; ++ni) mfma16(acc[mi][ni], af[mi], bf[ni]);
      __builtin_amdgcn_s_setprio(0);
    }
  }
  HZ();
  // epilogue: D[row = 4*lg + i][col = lr] per fragment (measured C/D layout)
#pragma unroll
  for (int mi = 0; mi < 4; ++mi)
#pragma unroll
    for (int ni = 0; ni < 4; ++ni)
#pragma unroll
      for (int i = 0; i < 4; ++i) {
        float val = acc[mi][ni][i];
        const int grow = m0 + wr0 + (mi << 4) + (lg << 2) + i;
        const int col = n0 + wc0 + (ni << 4) + lr;
        if (MODE == 0) {
          const int b = grow >> 11, s = grow & 2047;
          const int which = col >> 10, hh = (col >> 6) & 15, d = col & 63;
          const size_t base = (size_t)((b << 4) + hh);
          if (which == 2) {
            vtd[(base * 64 + d) * 2048 + s] = f2bf(val);
          } else {
            float other = __shfl_xor(val, 1);  // neighbor col (pair element)
            float2 cs = tab[(s << 5) + (d >> 1)];
            float r = (d & 1) ? fmaf(val, cs.x, other * cs.y)
                              : fmaf(val, cs.x, -other * cs.y);
            // fold (1/sqrt(HD)) * log2(e) into q so softmax runs in exp2 domain
            if (which == 0) r *= 0.18033688011f;
            u16* dst = which ? kd : qd;
            dst[(base * 2048 + s) * 64 + d] = f2bf(r);
          }
        } else {
          fout[(size_t)grow * 1024 + col] = val;
        }
      }
}

// ============================================================================
// Flash attention, bf16 MFMA. 1 block = (b,h,64-row q tile); 4 waves x 16 rows.
// Double-buffered K/V LDS with counted vmcnt(4); swapped QK^T; exp2-domain
// softmax with defer-max (threshold 8 log2-units -> P <= 256); packed-cvt P.
// ============================================================================
__global__ __launch_bounds__(256) void attn_mfma(
    const u16* __restrict__ q, const u16* __restrict__ k,
    const u16* __restrict__ vt, u16* __restrict__ ohi, u16* __restrict__ olo) {
  __shared__ __align__(16) char Ks[2][8192];   // [64 j][64 d] swizzled
  __shared__ __align__(16) char Vs[2][8192];   // [64 dd][64 j] swizzled
  __shared__ __align__(16) u16 Ps[4][16][72];  // per-wave P[q][j], pad 72
  const int bid = blockIdx.x;
  const int swz = (bid & 7) * 128 + (bid >> 3);  // XCD-aware remap (1024%8==0)
  const int qt = swz & 31;
  const int hh = (swz >> 5) & 15;
  const int b = swz >> 9;
  const int t = threadIdx.x;
  const int w = t >> 6;
  const int lane = t & 63;
  const int lr = lane & 15;
  const int lg = lane >> 4;

  const size_t bh = (size_t)((b << 4) + hh);
  const u16* qb = q + (bh * 2048 + (size_t)qt * 64 + w * 16) * 64;
  const u16* kb = k + bh * 2048 * 64;
  const u16* vb = vt + bh * 64 * 2048;

  // Q fragments (q rows = lr of this wave's 16; d slot = kk*32 + 8*lg + i)
  u32x4 qf[2];
  qf[0] = *(const u32x4*)(qb + lr * 64 + lg * 8);
  qf[1] = *(const u32x4*)(qb + lr * 64 + 32 + lg * 8);

  auto issue = [&](int kt_, int buf_) {
    const u16* ksrc = kb + kt_ * 4096;  // contiguous 64x64 tile
#pragma unroll
    for (int r = 0; r < 2; ++r) {
      const int row = (t >> 3) + (r << 5);
      const int g = (t & 7) ^ (row & 7);
      gld16(ksrc + row * 64 + (g << 3), &Ks[buf_][(r << 12) + (w << 10)]);
      gld16(vb + (size_t)row * 2048 + kt_ * 64 + (g << 3),
            &Vs[buf_][(r << 12) + (w << 10)]);
    }
  };

  f32x4 oacc[4];
#pragma unroll
  for (int ddb = 0; ddb < 4; ++ddb) oacc[ddb] = (f32x4)0.0f;
  float mrow = -3.0e38f, lrow = 0.0f;  // stats for q = lr (log2 domain)

  issue(0, 0);
  for (int kt = 0; kt < 32; ++kt) {
    const int cur = kt & 1;
    if (kt < 31) {
      issue(kt + 1, cur ^ 1);  // safe: buf cur^1 consumers done at kt-1 tail bar
      asm volatile("s_waitcnt vmcnt(4)" ::: "memory");  // tile kt landed
    } else {
      asm volatile("s_waitcnt vmcnt(0)" ::: "memory");
    }
    __syncthreads();
    const char* Kc = Ks[cur];
    const char* Vc = Vs[cur];
    // S^T[j][q] = K * Q^T : A-frag = K rows j, B-frag = Q (col q = lr)
    f32x4 sacc[4];
#pragma unroll
    for (int jb = 0; jb < 4; ++jb) sacc[jb] = (f32x4)0.0f;
#pragma unroll
    for (int kk = 0; kk < 2; ++kk) {
      u32x4 kf[4];
#pragma unroll
      for (int jb = 0; jb < 4; ++jb) {
        const int row = (jb << 4) + lr;
        kf[jb] = *(const u32x4*)(Kc + row * 128 +
                                 ((((kk << 2) + lg) ^ (row & 7)) << 4));
      }
      asm volatile("s_nop 1");
      __builtin_amdgcn_s_setprio(1);
#pragma unroll
      for (int jb = 0; jb < 4; ++jb) mfma16(sacc[jb], kf[jb], qf[kk]);
      __builtin_amdgcn_s_setprio(0);
    }
    HZ();
    // online softmax over j for this lane's q = lr (S^T row j = jb*16+4*lg+i)
    float pmax = -3.0e38f;
#pragma unroll
    for (int jb = 0; jb < 4; ++jb) {
      float m01 = fmaxf(sacc[jb][0], sacc[jb][1]);
      float m23 = fmaxf(sacc[jb][2], sacc[jb][3]);
      pmax = fmaxf(pmax, fmaxf(m01, m23));
    }
    pmax = fmaxf(pmax, __shfl_xor(pmax, 16));
    pmax = fmaxf(pmax, __shfl_xor(pmax, 32));
    // defer-max: only rescale when the running max grew by > 8 (P <= 2^8)
    if (__any(pmax > mrow + 8.0f)) {
      const float mnew = fmaxf(mrow, pmax);
      const float fac = EXP2(mrow - mnew);
      mrow = mnew;
      lrow *= fac;
      float fci[4];
#pragma unroll
      for (int i = 0; i < 4; ++i) fci[i] = __shfl(fac, (lg << 2) + i);
#pragma unroll
      for (int ddb = 0; ddb < 4; ++ddb)
#pragma unroll
        for (int i = 0; i < 4; ++i) oacc[ddb][i] *= fci[i];
    }
    float lsum = 0.0f;
#pragma unroll
    for (int jb = 0; jb < 4; ++jb) {
      const float p0 = EXP2(sacc[jb][0] - mrow);
      const float p1 = EXP2(sacc[jb][1] - mrow);
      const float p2 = EXP2(sacc[jb][2] - mrow);
      const float p3 = EXP2(sacc[jb][3] - mrow);
      lsum += (p0 + p1) + (p2 + p3);
      *(u32*)(&Ps[w][lr][(jb << 4) + (lg << 2)]) = pk2bf(p0, p1);
      *(u32*)(&Ps[w][lr][(jb << 4) + (lg << 2) + 2]) = pk2bf(p2, p3);
    }
    lsum += __shfl_xor(lsum, 16);
    lsum += __shfl_xor(lsum, 32);
    lrow += lsum;
    // PV: A = P[q=lr][j-slot], B = V^T rows dd; k-dim = j (slot maps match)
    asm volatile("s_nop 3");
#pragma unroll
    for (int kk = 0; kk < 2; ++kk) {
      const u32x4 pf = *(const u32x4*)(&Ps[w][lr][(kk << 5) + (lg << 3)]);
      __builtin_amdgcn_s_setprio(1);
#pragma unroll
      for (int ddb = 0; ddb < 4; ++ddb) {
        const int row = (ddb << 4) + lr;
        const u32x4 vf = *(const u32x4*)(Vc + row * 128 +
                                         ((((kk << 2) + lg) ^ (row & 7)) << 4));
        mfma16(oacc[ddb], pf, vf);
      }
      __builtin_amdgcn_s_setprio(0);
    }
    __syncthreads();  // all waves done reading cur -> free for kt+2's issue
  }
  HZ();
  // epilogue: normalize rows, split hi/lo bf16, write o[b][s][h*64+dd]
  const float invl = 1.0f / lrow;  // for q = lr
  float inv[4];
#pragma unroll
  for (int i = 0; i < 4; ++i) inv[i] = __shfl(invl, (lg << 2) + i);
#pragma unroll
  for (int ddb = 0; ddb < 4; ++ddb)
#pragma unroll
    for (int i = 0; i < 4; ++i) {
      const float vO = oacc[ddb][i] * inv[i];
      const u16 h = f2bf(vO);
      const u16 l = f2bf(vO - bf2f(h));
      const size_t srow =
          (size_t)(b * 2048 + (qt << 6) + (w << 4) + (lg << 2) + i);
      const int col = (hh << 6) + (ddb << 4) + lr;
      ohi[srow * 1024 + col] = h;
      olo[srow * 1024 + col] = l;
    }
}

extern "C" void kernel_launch(void* const* d_in, const int* in_sizes, int n_in,
                              void* d_out, int out_size, void* d_ws,
                              size_t ws_size, hipStream_t stream) {
  const float* x = (const float*)d_in[0];
  const float* w1 = (const float*)d_in[1];
  const float* w2 = (const float*)d_in[2];
  char* ws = (char*)d_ws;
  float2* tab = (float2*)(ws + TAB_B);
  u16* qbf = (u16*)(ws + QBF_B);
  u16* kbf = (u16*)(ws + KBF_B);
  u16* vtbf = (u16*)(ws + VTB_B);
  u16* w2hi = (u16*)(ws + W2HI_B);
  u16* w2lo = (u16*)(ws + W2LO_B);
  u16* xbf = (u16*)(ws + XBF_B);
  u16* w1bf = (u16*)(ws + W1BF_B);
  u16* ohi = (u16*)(ws + OHI_B);
  u16* olo = (u16*)(ws + OLO_B);
  float* out = (float*)d_out;

  prep_kernel<<<dim3(2304), dim3(256), 0, stream>>>(x, w1, w2, tab, xbf, w1bf,
                                                    w2hi, w2lo);
  gemm_bt<0><<<dim3(32 * 24), dim3(256), 0, stream>>>(
      xbf, xbf, w1bf, w1bf, 24, 16, tab, qbf, kbf, vtbf, nullptr);
  attn_mfma<<<dim3(1024), dim3(256), 0, stream>>>(qbf, kbf, vtbf, ohi, olo);
  gemm_bt<1><<<dim3(32 * 8), dim3(256), 0, stream>>>(
      ohi, olo, w2hi, w2lo, 8, 48, nullptr, nullptr, nullptr, nullptr, out);
}

// Round 6
// 163.996 us; speedup vs baseline: 1.2343x; 1.2343x over previous
//
#include <hip/hip_runtime.h>
#include <math.h>

typedef unsigned short u16;
typedef unsigned int u32;
typedef float f32x4 __attribute__((ext_vector_type(4)));
typedef float f32x16 __attribute__((ext_vector_type(16)));
typedef u32 u32x4 __attribute__((ext_vector_type(4)));

// ---- problem dims: B=2 S=2048 E=1024 H=16 HD=64 ----
static const size_t TAB_B  = 0;         // float2[2048][32]
static const size_t QBF_B  = 524288;    // bf16 [2][16][2048][64], pre-scaled 0.125*log2e
static const size_t KBF_B  = 8912896;   // bf16 [2][16][2048][64]
static const size_t VTB_B  = 17301504;  // bf16 [2][16][64][2048]  (V transposed)
static const size_t W2HI_B = 25690112;  // bf16 [1024][1024]
static const size_t W2LO_B = 27787264;
static const size_t XBF_B  = 29884416;  // bf16 x      (dead after QKV gemm)
static const size_t W1BF_B = 38273024;  // bf16 w1     (dead after QKV gemm)
static const size_t OHI_B  = 29884416;  // bf16 [4096][1024], reuses XBF
static const size_t OLO_B  = 38273024;  // bf16 [4096][1024], reuses W1BF

#if __has_builtin(__builtin_amdgcn_exp2f)
#define EXP2(x) __builtin_amdgcn_exp2f(x)
#else
#define EXP2(x) __expf(0.69314718056f * (x))
#endif

__device__ __forceinline__ u16 f2bf(float f) {
  u32 u = __builtin_bit_cast(u32, f);
  u += 0x7fffu + ((u >> 16) & 1u);
  return (u16)(u >> 16);
}
__device__ __forceinline__ float bf2f(u16 h) {
  return __builtin_bit_cast(float, (u32)h << 16);
}
// packed f32x2 -> bf16x2 (T12; single instruction, RNE)
__device__ __forceinline__ u32 cvtpk(float a, float b) {
  u32 r;
  asm("v_cvt_pk_bf16_f32 %0, %1, %2" : "=v"(r) : "v"(a), "v"(b));
  return r;  // a low16, b high16
}
// v_permlane32_swap_b32 a, b: exchanges a's HIGH lane-half with b's LOW half:
//   a' = {lanes0-31: a_lo, lanes32-63: b_lo}; b' = {lanes0-31: a_hi, hi: b_hi}
__device__ __forceinline__ void plswap(u32& a, u32& b) {
  asm volatile("v_permlane32_swap_b32 %0, %1" : "+v"(a), "+v"(b));
}
__device__ __forceinline__ void mfma16(f32x4& d, u32x4 a, u32x4 b) {
  asm volatile("v_mfma_f32_16x16x32_bf16 %0, %1, %2, %0"
               : "+v"(d)
               : "v"(a), "v"(b));
}
__device__ __forceinline__ void mfma32(f32x16& d, u32x4 a, u32x4 b) {
  asm volatile("v_mfma_f32_32x32x16_bf16 %0, %1, %2, %0"
               : "+v"(d)
               : "v"(a), "v"(b));
}
// async global->LDS, 16B per lane; lds dest = wave-uniform base (+lane*16 by HW)
__device__ __forceinline__ void gld16(const void* g, void* l) {
  __builtin_amdgcn_global_load_lds(
      (const __attribute__((address_space(1))) void*)(void*)g,
      (__attribute__((address_space(3))) void*)l, 16, 0, 0);
}
// MFMA->VALU read hazard fence (inline-asm MFMAs: compiler can't see latency)
#define HZ() asm volatile("s_nop 7\ns_nop 7\ns_nop 7\ns_nop 7")

// ============================================================================
// prep: rope table + bf16 converts, fused (one launch).
// ============================================================================
__global__ __launch_bounds__(256) void prep_kernel(
    const float* __restrict__ x, const float* __restrict__ w1,
    const float* __restrict__ w2, float2* __restrict__ tab,
    u16* __restrict__ xbf, u16* __restrict__ w1bf, u16* __restrict__ w2hi,
    u16* __restrict__ w2lo) {
  const int blk = blockIdx.x;
  const int t = threadIdx.x;
  if (blk < 256) {
    const int idx = (blk << 8) + t;
    const int s = idx >> 5, i = idx & 31;
    double theta = pow(10000.0, -((double)(2 * i)) / 64.0);
    float ang = (float)s * (float)theta;
    tab[idx] = make_float2(cosf(ang), sinf(ang));
  } else if (blk < 1280) {
    int i = ((blk - 256) << 8) + t;
#pragma unroll
    for (int r = 0; r < 4; ++r, i += 262144) {
      float4 v = ((const float4*)x)[i];
      ushort4 o;
      o.x = f2bf(v.x); o.y = f2bf(v.y); o.z = f2bf(v.z); o.w = f2bf(v.w);
      ((ushort4*)xbf)[i] = o;
    }
  } else if (blk < 2048) {
    int i = ((blk - 1280) << 8) + t;
#pragma unroll
    for (int r = 0; r < 4; ++r, i += 196608) {
      float4 v = ((const float4*)w1)[i];
      ushort4 o;
      o.x = f2bf(v.x); o.y = f2bf(v.y); o.z = f2bf(v.z); o.w = f2bf(v.w);
      ((ushort4*)w1bf)[i] = o;
    }
  } else {
    int i = ((blk - 2048) << 8) + t;
#pragma unroll
    for (int r = 0; r < 4; ++r, i += 65536) {
      float4 v = ((const float4*)w2)[i];
      ushort4 h, l;
      h.x = f2bf(v.x); h.y = f2bf(v.y); h.z = f2bf(v.z); h.w = f2bf(v.w);
      l.x = f2bf(v.x - bf2f(h.x));
      l.y = f2bf(v.y - bf2f(h.y));
      l.z = f2bf(v.z - bf2f(h.z));
      l.w = f2bf(v.w - bf2f(h.w));
      ((ushort4*)w2hi)[i] = h;
      ((ushort4*)w2lo)[i] = l;
    }
  }
}

// ============================================================================
// B^T GEMM (unchanged from round 2): 128x128 tile, BK=64, 4 waves.
// MODE 0: 1-pass, epilogue = RoPE + scatter q(scaled)/k/vT bf16.
// MODE 1: 3-pass hi/lo split, epilogue = f32 store to out.
// ============================================================================
template <int MODE>
__global__ __launch_bounds__(256) void gemm_bt(
    const u16* __restrict__ Ahi, const u16* __restrict__ Alo,
    const u16* __restrict__ Bhi, const u16* __restrict__ Blo, int nbn, int nkb,
    const float2* __restrict__ tab, u16* __restrict__ qd, u16* __restrict__ kd,
    u16* __restrict__ vtd, float* __restrict__ fout) {
  __shared__ __align__(16) char As[16384];
  __shared__ __align__(16) char Bs[16384];
  const int bm = blockIdx.x / nbn;
  const int bn = blockIdx.x % nbn;
  const int m0 = bm << 7;
  const int n0 = bn << 7;
  const int t = threadIdx.x;
  const int w = t >> 6;
  const int lane = t & 63;
  const int lr = lane & 15;
  const int lg = lane >> 4;
  const int wr0 = (w >> 1) << 6;
  const int wc0 = (w & 1) << 6;
  const int srow0 = t >> 3;
  const int sblk = t & 7;

  f32x4 acc[4][4];
#pragma unroll
  for (int mi = 0; mi < 4; ++mi)
#pragma unroll
    for (int ni = 0; ni < 4; ++ni) acc[mi][ni] = (f32x4)0.0f;

  for (int kb = 0; kb < nkb; ++kb) {
    const int pass = kb >> 4;
    const int k0 = (kb & 15) << 6;
    const u16* Ap = (MODE == 1 && pass == 2) ? Alo : Ahi;
    const u16* Bp = (MODE == 1 && pass == 1) ? Blo : Bhi;
    if (kb) __syncthreads();
#pragma unroll
    for (int r = 0; r < 4; ++r) {
      const int row = srow0 + (r << 5);
      const int g = sblk ^ (row & 7);
      gld16(Ap + (size_t)(m0 + row) * 1024 + k0 + (g << 3),
            As + (r << 12) + (w << 10));
      gld16(Bp + (size_t)(n0 + row) * 1024 + k0 + (g << 3),
            Bs + (r << 12) + (w << 10));
    }
    asm volatile("s_waitcnt vmcnt(0)" ::: "memory");
    __syncthreads();
#pragma unroll
    for (int kk = 0; kk < 2; ++kk) {
      u32x4 af[4], bf[4];
#pragma unroll
      for (int mi = 0; mi < 4; ++mi) {
        const int row = wr0 + (mi << 4) + lr;
        af[mi] = *(const u32x4*)(As + row * 128 +
                                 ((((kk << 2) + lg) ^ (row & 7)) << 4));
      }
#pragma unroll
      for (int ni = 0; ni < 4; ++ni) {
        const int row = wc0 + (ni << 4) + lr;
        bf[ni] = *(const u32x4*)(Bs + row * 128 +
                                 ((((kk << 2) + lg) ^ (row & 7)) << 4));
      }
      asm volatile("s_nop 1");
      __builtin_amdgcn_s_setprio(1);
#pragma unroll
      for (int mi = 0; mi < 4; ++mi)
#pragma unroll
        for (int ni = 0; ni < 4; ++ni) mfma16(acc[mi][ni], af[mi], bf[ni]);
      __builtin_amdgcn_s_setprio(0);
    }
  }
  HZ();
#pragma unroll
  for (int mi = 0; mi < 4; ++mi)
#pragma unroll
    for (int ni = 0; ni < 4; ++ni)
#pragma unroll
      for (int i = 0; i < 4; ++i) {
        float val = acc[mi][ni][i];
        const int grow = m0 + wr0 + (mi << 4) + (lg << 2) + i;
        const int col = n0 + wc0 + (ni << 4) + lr;
        if (MODE == 0) {
          const int b = grow >> 11, s = grow & 2047;
          const int which = col >> 10, hh = (col >> 6) & 15, d = col & 63;
          const size_t base = (size_t)((b << 4) + hh);
          if (which == 2) {
            vtd[(base * 64 + d) * 2048 + s] = f2bf(val);
          } else {
            float other = __shfl_xor(val, 1);
            float2 cs = tab[(s << 5) + (d >> 1)];
            float r = (d & 1) ? fmaf(val, cs.x, other * cs.y)
                              : fmaf(val, cs.x, -other * cs.y);
            // fold (1/sqrt(HD)) * log2(e) into q -> softmax in exp2 domain
            if (which == 0) r *= 0.18033688011f;
            u16* dst = which ? kd : qd;
            dst[(base * 2048 + s) * 64 + d] = f2bf(r);
          }
        } else {
          fout[(size_t)grow * 1024 + col] = val;
        }
      }
}

// ============================================================================
// Flash attention v2: 32x32 MFMA, in-register softmax (T12), no P LDS.
// 1 block = (b,h,128-row q range); 4 waves x 32 q rows. Grid 512.
// S^T = K*Q^T -> lane holds 32 scores of one q row (col=lane&31).
// PA frags built via cvt_pk + permlane32_swap. Dbuf K/V, counted vmcnt.
// ============================================================================
__global__ __launch_bounds__(256) void attn_mfma(
    const u16* __restrict__ q, const u16* __restrict__ k,
    const u16* __restrict__ vt, u16* __restrict__ ohi, u16* __restrict__ olo) {
  __shared__ __align__(16) char Ks[2][8192];  // [64 j][64 d] swizzled
  __shared__ __align__(16) char Vs[2][8192];  // [64 dd][64 j] swizzled
  const int bid = blockIdx.x;
  const int swz = (bid & 7) * 64 + (bid >> 3);  // XCD remap (512%8==0)
  const int qt = swz & 15;
  const int hh = (swz >> 4) & 15;
  const int b = swz >> 8;
  const int t = threadIdx.x;
  const int w = t >> 6;
  const int lane = t & 63;
  const int lq = lane & 31;  // q col / j row / dd col within 32
  const int h = lane >> 5;   // lane half

  const size_t bh = (size_t)((b << 4) + hh);
  const u16* qb = q + (bh * 2048 + (size_t)(qt * 128 + w * 32)) * 64;
  const u16* kb = k + bh * 2048 * 64;
  const u16* vb = vt + bh * 64 * 2048;

  // Q B-frags: col q=lq, d slots = dk*16 + 8*h + 0..7
  u32x4 qf[4];
#pragma unroll
  for (int dk = 0; dk < 4; ++dk)
    qf[dk] = *(const u32x4*)(qb + lq * 64 + dk * 16 + h * 8);

  auto issue = [&](int kt_, int buf_) {
    const u16* ksrc = kb + kt_ * 4096;
#pragma unroll
    for (int r = 0; r < 2; ++r) {
      const int row = (t >> 3) + (r << 5);
      const int g = (t & 7) ^ (row & 7);
      gld16(ksrc + row * 64 + (g << 3), &Ks[buf_][(r << 12) + (w << 10)]);
      gld16(vb + (size_t)row * 2048 + kt_ * 64 + (g << 3),
            &Vs[buf_][(r << 12) + (w << 10)]);
    }
  };

  f32x16 oacc0 = (f32x16)0.0f, oacc1 = (f32x16)0.0f;  // O[q][dd], dd blocks 0/1
  float mrow = -3.0e38f, lrow = 0.0f;  // stats for q=lq (log2 domain)

  issue(0, 0);
  for (int kt = 0; kt < 32; ++kt) {
    const int cur = kt & 1;
    if (kt < 31) {
      issue(kt + 1, cur ^ 1);
      asm volatile("s_waitcnt vmcnt(4)" ::: "memory");
    } else {
      asm volatile("s_waitcnt vmcnt(0)" ::: "memory");
    }
    __syncthreads();
    const char* Kc = Ks[cur];
    const char* Vc = Vs[cur];
    // S^T tiles: rows j (2 blocks of 32), cols q
    f32x16 s0 = (f32x16)0.0f, s1 = (f32x16)0.0f;
    __builtin_amdgcn_s_setprio(1);
#pragma unroll
    for (int dk = 0; dk < 4; ++dk) {
      const int c = (dk << 1) + h;
      u32x4 kf0 = *(const u32x4*)(Kc + lq * 128 + ((c ^ (lq & 7)) << 4));
      u32x4 kf1 = *(const u32x4*)(Kc + (32 + lq) * 128 + ((c ^ (lq & 7)) << 4));
      mfma32(s0, kf0, qf[dk]);
      mfma32(s1, kf1, qf[dk]);
    }
    __builtin_amdgcn_s_setprio(0);
    HZ();
    // in-lane softmax for q=lq: rows split lo/hi half -> one shfl_xor(32)
    float pmax = s0[0];
#pragma unroll
    for (int i = 1; i < 16; ++i) pmax = fmaxf(pmax, s0[i]);
#pragma unroll
    for (int i = 0; i < 16; ++i) pmax = fmaxf(pmax, s1[i]);
    pmax = fmaxf(pmax, __shfl_xor(pmax, 32));
    // defer-max: rescale only when running max grew > 8 (P <= 2^8)
    if (__any(pmax > mrow + 8.0f)) {
      const float mnew = fmaxf(mrow, pmax);
      const float fac = EXP2(mrow - mnew);
      mrow = mnew;
      lrow *= fac;
#pragma unroll
      for (int r = 0; r < 16; ++r) {
        const float fr = __shfl(fac, (r & 3) + 8 * (r >> 2) + 4 * h);
        oacc0[r] *= fr;
        oacc1[r] *= fr;
      }
    }
    float lsum = 0.0f;
#pragma unroll
    for (int i = 0; i < 16; ++i) {
      s0[i] = EXP2(s0[i] - mrow);
      lsum += s0[i];
    }
#pragma unroll
    for (int i = 0; i < 16; ++i) {
      s1[i] = EXP2(s1[i] - mrow);
      lsum += s1[i];
    }
    lsum += __shfl_xor(lsum, 32);
    lrow += lsum;
    // T12: build PA frags. Lane (lq,h) holds P[lq][j=(i&3)+8*(i>>2)+4h] in
    // s0/s1[i]. cvt_pk words: w0=j{0,1|4,5} w1=j{2,3|6,7} w2=j{8,9|12,13}
    // w3=j{10,11|14,15} (lo-half|hi-half contents). plswap(w0,w2) yields
    // w0'=j{0,1|8,9}=pa[0] slot, w2'=j{4,5|12,13}=pa[2] slot (k=h*8+i). Same
    // for (w1,w3),(w4,w6),(w5,w7).
    u32x4 pa0, pa1, pa2, pa3;
    {
      u32 w0 = cvtpk(s0[0], s0[1]), w1 = cvtpk(s0[2], s0[3]);
      u32 w2 = cvtpk(s0[4], s0[5]), w3 = cvtpk(s0[6], s0[7]);
      u32 w4 = cvtpk(s0[8], s0[9]), w5 = cvtpk(s0[10], s0[11]);
      u32 w6 = cvtpk(s0[12], s0[13]), w7 = cvtpk(s0[14], s0[15]);
      plswap(w0, w2);
      plswap(w1, w3);
      plswap(w4, w6);
      plswap(w5, w7);
      pa0[0] = w0; pa0[1] = w1; pa0[2] = w2; pa0[3] = w3;
      pa1[0] = w4; pa1[1] = w5; pa1[2] = w6; pa1[3] = w7;
      u32 y0 = cvtpk(s1[0], s1[1]), y1 = cvtpk(s1[2], s1[3]);
      u32 y2 = cvtpk(s1[4], s1[5]), y3 = cvtpk(s1[6], s1[7]);
      u32 y4 = cvtpk(s1[8], s1[9]), y5 = cvtpk(s1[10], s1[11]);
      u32 y6 = cvtpk(s1[12], s1[13]), y7 = cvtpk(s1[14], s1[15]);
      plswap(y0, y2);
      plswap(y1, y3);
      plswap(y4, y6);
      plswap(y5, y7);
      pa2[0] = y0; pa2[1] = y1; pa2[2] = y2; pa2[3] = y3;
      pa3[0] = y4; pa3[1] = y5; pa3[2] = y6; pa3[3] = y7;
    }
    // PV: O[q][dd] += P * V^T ; B-frag col dd=lq(+32), k slots j
    asm volatile("s_nop 2");
    __builtin_amdgcn_s_setprio(1);
#define PVSTEP(kbk, paf)                                                      \
  {                                                                           \
    const int c = ((kbk) << 1) + h;                                           \
    u32x4 vf0 = *(const u32x4*)(Vc + lq * 128 + ((c ^ (lq & 7)) << 4));       \
    u32x4 vf1 =                                                               \
        *(const u32x4*)(Vc + (32 + lq) * 128 + ((c ^ (lq & 7)) << 4));        \
    mfma32(oacc0, paf, vf0);                                                  \
    mfma32(oacc1, paf, vf1);                                                  \
  }
    PVSTEP(0, pa0)
    PVSTEP(1, pa1)
    PVSTEP(2, pa2)
    PVSTEP(3, pa3)
#undef PVSTEP
    __builtin_amdgcn_s_setprio(0);
    __syncthreads();
  }
  HZ();
  // epilogue: normalize (per-reg row q), split hi/lo bf16, store
  const float invl = 1.0f / lrow;
#pragma unroll
  for (int r = 0; r < 16; ++r) {
    const int qr = (r & 3) + 8 * (r >> 2) + 4 * h;
    const float fr = __shfl(invl, qr);
    const size_t srow = (size_t)(b * 2048 + (qt << 7) + (w << 5) + qr);
    const float v0 = oacc0[r] * fr;
    const float v1 = oacc1[r] * fr;
    const u16 h0 = f2bf(v0), h1 = f2bf(v1);
    const size_t base = srow * 1024 + (hh << 6) + lq;
    ohi[base] = h0;
    ohi[base + 32] = h1;
    olo[base] = f2bf(v0 - bf2f(h0));
    olo[base + 32] = f2bf(v1 - bf2f(h1));
  }
}

extern "C" void kernel_launch(void* const* d_in, const int* in_sizes, int n_in,
                              void* d_out, int out_size, void* d_ws,
                              size_t ws_size, hipStream_t stream) {
  const float* x = (const float*)d_in[0];
  const float* w1 = (const float*)d_in[1];
  const float* w2 = (const float*)d_in[2];
  char* ws = (char*)d_ws;
  float2* tab = (float2*)(ws + TAB_B);
  u16* qbf = (u16*)(ws + QBF_B);
  u16* kbf = (u16*)(ws + KBF_B);
  u16* vtbf = (u16*)(ws + VTB_B);
  u16* w2hi = (u16*)(ws + W2HI_B);
  u16* w2lo = (u16*)(ws + W2LO_B);
  u16* xbf = (u16*)(ws + XBF_B);
  u16* w1bf = (u16*)(ws + W1BF_B);
  u16* ohi = (u16*)(ws + OHI_B);
  u16* olo = (u16*)(ws + OLO_B);
  float* out = (float*)d_out;

  prep_kernel<<<dim3(2304), dim3(256), 0, stream>>>(x, w1, w2, tab, xbf, w1bf,
                                                    w2hi, w2lo);
  gemm_bt<0><<<dim3(32 * 24), dim3(256), 0, stream>>>(
      xbf, xbf, w1bf, w1bf, 24, 16, tab, qbf, kbf, vtbf, nullptr);
  attn_mfma<<<dim3(512), dim3(256), 0, stream>>>(qbf, kbf, vtbf, ohi, olo);
  gemm_bt<1><<<dim3(32 * 8), dim3(256), 0, stream>>>(
      ohi, olo, w2hi, w2lo, 8, 48, nullptr, nullptr, nullptr, nullptr, out);
}

// Round 9
// 133.027 us; speedup vs baseline: 1.5216x; 1.2328x over previous
//
#include <hip/hip_runtime.h>
#include <math.h>

typedef unsigned short u16;
typedef unsigned int u32;
typedef float f32x4 __attribute__((ext_vector_type(4)));
typedef float f32x16 __attribute__((ext_vector_type(16)));
typedef u32 u32x4 __attribute__((ext_vector_type(4)));

// ---- problem dims: B=2 S=2048 E=1024 H=16 HD=64 ----
static const size_t TAB_B  = 0;         // float2[2048][32]
static const size_t QBF_B  = 524288;    // bf16 [2][16][2048][64], pre-scaled 0.125*log2e
static const size_t KBF_B  = 8912896;   // bf16 [2][16][2048][64]
static const size_t VTB_B  = 17301504;  // bf16 [2][16][64][2048]  (V transposed)
static const size_t W2H_B  = 25690112;  // fp16 [1024][1024]
static const size_t XBF_B  = 29884416;  // bf16 x      (dead after QKV gemm)
static const size_t W1BF_B = 38273024;  // bf16 w1     (dead after QKV gemm)
static const size_t O16_B  = 29884416;  // fp16 [4096][1024], reuses XBF

#if __has_builtin(__builtin_amdgcn_exp2f)
#define EXP2(x) __builtin_amdgcn_exp2f(x)
#else
#define EXP2(x) __expf(0.69314718056f * (x))
#endif

__device__ __forceinline__ u16 f2bf(float f) {
  u32 u = __builtin_bit_cast(u32, f);
  u += 0x7fffu + ((u >> 16) & 1u);
  return (u16)(u >> 16);
}
__device__ __forceinline__ float bf2f(u16 h) {
  return __builtin_bit_cast(float, (u32)h << 16);
}
__device__ __forceinline__ u16 f2h(float f) {
  _Float16 h = (_Float16)f;
  return __builtin_bit_cast(u16, h);
}
// packed f32x2 -> bf16x2 (T12; single instruction, RNE)
__device__ __forceinline__ u32 cvtpk(float a, float b) {
  u32 r;
  asm("v_cvt_pk_bf16_f32 %0, %1, %2" : "=v"(r) : "v"(a), "v"(b));
  return r;  // a low16, b high16
}
// v_permlane32_swap_b32 a, b: a' = {lo: a_lo, hi: b_lo}; b' = {lo: a_hi, hi: b_hi}
__device__ __forceinline__ void plswap(u32& a, u32& b) {
  asm volatile("v_permlane32_swap_b32 %0, %1" : "+v"(a), "+v"(b));
}
__device__ __forceinline__ void mfma16(f32x4& d, u32x4 a, u32x4 b) {
  asm volatile("v_mfma_f32_16x16x32_bf16 %0, %1, %2, %0"
               : "+v"(d)
               : "v"(a), "v"(b));
}
__device__ __forceinline__ void mfma16f(f32x4& d, u32x4 a, u32x4 b) {
  asm volatile("v_mfma_f32_16x16x32_f16 %0, %1, %2, %0"
               : "+v"(d)
               : "v"(a), "v"(b));
}
__device__ __forceinline__ void mfma32(f32x16& d, u32x4 a, u32x4 b) {
  asm volatile("v_mfma_f32_32x32x16_bf16 %0, %1, %2, %0"
               : "+v"(d)
               : "v"(a), "v"(b));
}
// async global->LDS, 16B per lane; lds dest = wave-uniform base (+lane*16 by HW)
__device__ __forceinline__ void gld16(const void* g, void* l) {
  __builtin_amdgcn_global_load_lds(
      (const __attribute__((address_space(1))) void*)(void*)g,
      (__attribute__((address_space(3))) void*)l, 16, 0, 0);
}
// MFMA->VALU read hazard fence + scheduling pin (rule #18)
#define HZ()                                            \
  do {                                                  \
    asm volatile("s_nop 7\ns_nop 7\ns_nop 7\ns_nop 7"); \
    __builtin_amdgcn_sched_barrier(0);                  \
  } while (0)

// ============================================================================
// prep: rope table + bf16/fp16 converts, fused (one launch).
// ============================================================================
__global__ __launch_bounds__(256) void prep_kernel(
    const float* __restrict__ x, const float* __restrict__ w1,
    const float* __restrict__ w2, float2* __restrict__ tab,
    u16* __restrict__ xbf, u16* __restrict__ w1bf, u16* __restrict__ w2h) {
  const int blk = blockIdx.x;
  const int t = threadIdx.x;
  if (blk < 256) {
    const int idx = (blk << 8) + t;
    const int s = idx >> 5, i = idx & 31;
    double theta = pow(10000.0, -((double)(2 * i)) / 64.0);
    float ang = (float)s * (float)theta;
    tab[idx] = make_float2(cosf(ang), sinf(ang));
  } else if (blk < 1280) {
    int i = ((blk - 256) << 8) + t;
#pragma unroll
    for (int r = 0; r < 4; ++r, i += 262144) {
      float4 v = ((const float4*)x)[i];
      ushort4 o;
      o.x = f2bf(v.x); o.y = f2bf(v.y); o.z = f2bf(v.z); o.w = f2bf(v.w);
      ((ushort4*)xbf)[i] = o;
    }
  } else if (blk < 2048) {
    int i = ((blk - 1280) << 8) + t;
#pragma unroll
    for (int r = 0; r < 4; ++r, i += 196608) {
      float4 v = ((const float4*)w1)[i];
      ushort4 o;
      o.x = f2bf(v.x); o.y = f2bf(v.y); o.z = f2bf(v.z); o.w = f2bf(v.w);
      ((ushort4*)w1bf)[i] = o;
    }
  } else {
    int i = ((blk - 2048) << 8) + t;
#pragma unroll
    for (int r = 0; r < 4; ++r, i += 65536) {
      float4 v = ((const float4*)w2)[i];
      ushort4 o;
      o.x = f2h(v.x); o.y = f2h(v.y); o.z = f2h(v.z); o.w = f2h(v.w);
      ((ushort4*)w2h)[i] = o;
    }
  }
}

// ============================================================================
// B^T GEMM: 128x128 tile, BK=64, 4 waves (2x2 of 64x64), gld_lds staging.
// MODE 0 (bf16): epilogue = RoPE + scatter q(scaled)/k/vT bf16.
// MODE 1 (fp16): single pass, epilogue = f32 store to out.
// ============================================================================
template <int MODE>
__global__ __launch_bounds__(256) void gemm_bt(
    const u16* __restrict__ Ahi, const u16* __restrict__ Bhi, int nbn, int nkb,
    const float2* __restrict__ tab, u16* __restrict__ qd, u16* __restrict__ kd,
    u16* __restrict__ vtd, float* __restrict__ fout) {
  __shared__ __align__(16) char As[16384];
  __shared__ __align__(16) char Bs[16384];
  const int bm = blockIdx.x / nbn;
  const int bn = blockIdx.x % nbn;
  const int m0 = bm << 7;
  const int n0 = bn << 7;
  const int t = threadIdx.x;
  const int w = t >> 6;
  const int lane = t & 63;
  const int lr = lane & 15;
  const int lg = lane >> 4;
  const int wr0 = (w >> 1) << 6;
  const int wc0 = (w & 1) << 6;
  const int srow0 = t >> 3;
  const int sblk = t & 7;

  f32x4 acc[4][4];
#pragma unroll
  for (int mi = 0; mi < 4; ++mi)
#pragma unroll
    for (int ni = 0; ni < 4; ++ni) acc[mi][ni] = (f32x4)0.0f;

  for (int kb = 0; kb < nkb; ++kb) {
    const int k0 = kb << 6;
    if (kb) __syncthreads();
#pragma unroll
    for (int r = 0; r < 4; ++r) {
      const int row = srow0 + (r << 5);
      const int g = sblk ^ (row & 7);
      gld16(Ahi + (size_t)(m0 + row) * 1024 + k0 + (g << 3),
            As + (r << 12) + (w << 10));
      gld16(Bhi + (size_t)(n0 + row) * 1024 + k0 + (g << 3),
            Bs + (r << 12) + (w << 10));
    }
    asm volatile("s_waitcnt vmcnt(0)" ::: "memory");
    __syncthreads();
#pragma unroll
    for (int kk = 0; kk < 2; ++kk) {
      u32x4 af[4], bf[4];
#pragma unroll
      for (int mi = 0; mi < 4; ++mi) {
        const int row = wr0 + (mi << 4) + lr;
        af[mi] = *(const u32x4*)(As + row * 128 +
                                 ((((kk << 2) + lg) ^ (row & 7)) << 4));
      }
#pragma unroll
      for (int ni = 0; ni < 4; ++ni) {
        const int row = wc0 + (ni << 4) + lr;
        bf[ni] = *(const u32x4*)(Bs + row * 128 +
                                 ((((kk << 2) + lg) ^ (row & 7)) << 4));
      }
      asm volatile("s_nop 1");
      __builtin_amdgcn_s_setprio(1);
#pragma unroll
      for (int mi = 0; mi < 4; ++mi)
#pragma unroll
        for (int ni = 0; ni < 4; ++ni) {
          if constexpr (MODE == 1)
            mfma16f(acc[mi][ni], af[mi], bf[ni]);
          else
            mfma16(acc[mi][ni], af[mi], bf[ni]);
        }
      __builtin_amdgcn_s_setprio(0);
    }
  }
  HZ();
#pragma unroll
  for (int mi = 0; mi < 4; ++mi)
#pragma unroll
    for (int ni = 0; ni < 4; ++ni)
#pragma unroll
      for (int i = 0; i < 4; ++i) {
        float val = acc[mi][ni][i];
        const int grow = m0 + wr0 + (mi << 4) + (lg << 2) + i;
        const int col = n0 + wc0 + (ni << 4) + lr;
        if (MODE == 0) {
          const int b = grow >> 11, s = grow & 2047;
          const int which = col >> 10, hh = (col >> 6) & 15, d = col & 63;
          const size_t base = (size_t)((b << 4) + hh);
          if (which == 2) {
            vtd[(base * 64 + d) * 2048 + s] = f2bf(val);
          } else {
            float other = __shfl_xor(val, 1);
            float2 cs = tab[(s << 5) + (d >> 1)];
            float r = (d & 1) ? fmaf(val, cs.x, other * cs.y)
                              : fmaf(val, cs.x, -other * cs.y);
            // fold (1/sqrt(HD)) * log2(e) into q -> softmax in exp2 domain
            if (which == 0) r *= 0.18033688011f;
            u16* dst = which ? kd : qd;
            dst[(base * 2048 + s) * 64 + d] = f2bf(r);
          }
        } else {
          fout[(size_t)grow * 1024 + col] = val;
        }
      }
}

// ============================================================================
// Flash attention (round-6 proven body): 32x32 MFMA, in-register softmax
// (T12), LDS-staged K/V with double buffer + counted vmcnt(4). 1 block =
// (b,h,128 q rows); 4 waves x 32 q rows. Grid 512. Epilogue: fp16 o16.
// ============================================================================
__global__ __launch_bounds__(256) void attn_mfma(
    const u16* __restrict__ q, const u16* __restrict__ k,
    const u16* __restrict__ vt, u16* __restrict__ o16) {
  __shared__ __align__(16) char Ks[2][8192];  // [64 j][64 d] swizzled
  __shared__ __align__(16) char Vs[2][8192];  // [64 dd][64 j] swizzled
  const int bid = blockIdx.x;
  const int swz = (bid & 7) * 64 + (bid >> 3);  // XCD remap (512%8==0)
  const int qt = swz & 15;
  const int hh = (swz >> 4) & 15;
  const int b = swz >> 8;
  const int t = threadIdx.x;
  const int w = t >> 6;
  const int lane = t & 63;
  const int lq = lane & 31;  // q col / j row / dd row within 32
  const int h = lane >> 5;   // lane half

  const size_t bh = (size_t)((b << 4) + hh);
  const u16* qb = q + (bh * 2048 + (size_t)(qt * 128 + w * 32)) * 64;
  const u16* kb = k + bh * 2048 * 64;
  const u16* vb = vt + bh * 64 * 2048;

  // Q B-frags: col q=lq, d slots = dk*16 + 8*h + 0..7
  u32x4 qf[4];
#pragma unroll
  for (int dk = 0; dk < 4; ++dk)
    qf[dk] = *(const u32x4*)(qb + lq * 64 + dk * 16 + h * 8);

  auto issue = [&](int kt_, int buf_) {
    const u16* ksrc = kb + kt_ * 4096;
#pragma unroll
    for (int r = 0; r < 2; ++r) {
      const int row = (t >> 3) + (r << 5);
      const int g = (t & 7) ^ (row & 7);
      gld16(ksrc + row * 64 + (g << 3), &Ks[buf_][(r << 12) + (w << 10)]);
      gld16(vb + (size_t)row * 2048 + kt_ * 64 + (g << 3),
            &Vs[buf_][(r << 12) + (w << 10)]);
    }
  };

  f32x16 oacc0 = (f32x16)0.0f, oacc1 = (f32x16)0.0f;
  float mrow = -3.0e38f, lrow = 0.0f;  // log2 domain

  issue(0, 0);
  for (int kt = 0; kt < 32; ++kt) {
    const int cur = kt & 1;
    if (kt < 31) {
      issue(kt + 1, cur ^ 1);
      asm volatile("s_waitcnt vmcnt(4)" ::: "memory");
    } else {
      asm volatile("s_waitcnt vmcnt(0)" ::: "memory");
    }
    __syncthreads();
    const char* Kc = Ks[cur];
    const char* Vc = Vs[cur];
    // S^T tiles: rows j (2 blocks of 32), cols q
    f32x16 s0 = (f32x16)0.0f, s1 = (f32x16)0.0f;
    __builtin_amdgcn_s_setprio(1);
#pragma unroll
    for (int dk = 0; dk < 4; ++dk) {
      const int c = (dk << 1) + h;
      u32x4 kf0 = *(const u32x4*)(Kc + lq * 128 + ((c ^ (lq & 7)) << 4));
      u32x4 kf1 = *(const u32x4*)(Kc + (32 + lq) * 128 + ((c ^ (lq & 7)) << 4));
      mfma32(s0, kf0, qf[dk]);
      mfma32(s1, kf1, qf[dk]);
    }
    __builtin_amdgcn_s_setprio(0);
    HZ();
    // in-lane softmax for q=lq: rows split lo/hi half -> one shfl_xor(32)
    float pmax = s0[0];
#pragma unroll
    for (int i = 1; i < 16; ++i) pmax = fmaxf(pmax, s0[i]);
#pragma unroll
    for (int i = 0; i < 16; ++i) pmax = fmaxf(pmax, s1[i]);
    pmax = fmaxf(pmax, __shfl_xor(pmax, 32));
    // defer-max: rescale only when running max grew > 8 (P <= 2^8)
    if (__any(pmax > mrow + 8.0f)) {
      const float mnew = fmaxf(mrow, pmax);
      const float fac = EXP2(mrow - mnew);
      mrow = mnew;
      lrow *= fac;
#pragma unroll
      for (int r = 0; r < 16; ++r) {
        const float fr = __shfl(fac, (r & 3) + 8 * (r >> 2) + 4 * h);
        oacc0[r] *= fr;
        oacc1[r] *= fr;
      }
    }
    float lsum = 0.0f;
#pragma unroll
    for (int i = 0; i < 16; ++i) {
      s0[i] = EXP2(s0[i] - mrow);
      lsum += s0[i];
    }
#pragma unroll
    for (int i = 0; i < 16; ++i) {
      s1[i] = EXP2(s1[i] - mrow);
      lsum += s1[i];
    }
    lsum += __shfl_xor(lsum, 32);
    lrow += lsum;
    // T12: build PA frags. Lane (lq,h) holds P[lq][j=(i&3)+8*(i>>2)+4h] in
    // s0/s1[i]. plswap(w0,w2): w0'=j{0,1|8,9}, w2'=j{4,5|12,13} (k=h*8+i).
    u32x4 pa0, pa1, pa2, pa3;
    {
      u32 w0 = cvtpk(s0[0], s0[1]), w1 = cvtpk(s0[2], s0[3]);
      u32 w2 = cvtpk(s0[4], s0[5]), w3 = cvtpk(s0[6], s0[7]);
      u32 w4 = cvtpk(s0[8], s0[9]), w5 = cvtpk(s0[10], s0[11]);
      u32 w6 = cvtpk(s0[12], s0[13]), w7 = cvtpk(s0[14], s0[15]);
      plswap(w0, w2);
      plswap(w1, w3);
      plswap(w4, w6);
      plswap(w5, w7);
      pa0[0] = w0; pa0[1] = w1; pa0[2] = w2; pa0[3] = w3;
      pa1[0] = w4; pa1[1] = w5; pa1[2] = w6; pa1[3] = w7;
      u32 y0 = cvtpk(s1[0], s1[1]), y1 = cvtpk(s1[2], s1[3]);
      u32 y2 = cvtpk(s1[4], s1[5]), y3 = cvtpk(s1[6], s1[7]);
      u32 y4 = cvtpk(s1[8], s1[9]), y5 = cvtpk(s1[10], s1[11]);
      u32 y6 = cvtpk(s1[12], s1[13]), y7 = cvtpk(s1[14], s1[15]);
      plswap(y0, y2);
      plswap(y1, y3);
      plswap(y4, y6);
      plswap(y5, y7);
      pa2[0] = y0; pa2[1] = y1; pa2[2] = y2; pa2[3] = y3;
      pa3[0] = y4; pa3[1] = y5; pa3[2] = y6; pa3[3] = y7;
    }
    // PV: O[q][dd] += P * V^T ; B-frag col dd=lq(+32), k slots j
    asm volatile("s_nop 2");
    __builtin_amdgcn_s_setprio(1);
#define PVSTEP(kbk, paf)                                                      \
  {                                                                           \
    const int c = ((kbk) << 1) + h;                                           \
    u32x4 vf0 = *(const u32x4*)(Vc + lq * 128 + ((c ^ (lq & 7)) << 4));       \
    u32x4 vf1 =                                                               \
        *(const u32x4*)(Vc + (32 + lq) * 128 + ((c ^ (lq & 7)) << 4));        \
    mfma32(oacc0, paf, vf0);                                                  \
    mfma32(oacc1, paf, vf1);                                                  \
  }
    PVSTEP(0, pa0)
    PVSTEP(1, pa1)
    PVSTEP(2, pa2)
    PVSTEP(3, pa3)
#undef PVSTEP
    __builtin_amdgcn_s_setprio(0);
    __syncthreads();
  }
  HZ();
  // epilogue: normalize (per-reg row q), fp16 store
  const float invl = 1.0f / lrow;
#pragma unroll
  for (int r = 0; r < 16; ++r) {
    const int qr = (r & 3) + 8 * (r >> 2) + 4 * h;
    const float fr = __shfl(invl, qr);
    const size_t srow = (size_t)(b * 2048 + (qt << 7) + (w << 5) + qr);
    const size_t base = srow * 1024 + (hh << 6) + lq;
    o16[base] = f2h(oacc0[r] * fr);
    o16[base + 32] = f2h(oacc1[r] * fr);
  }
}

extern "C" void kernel_launch(void* const* d_in, const int* in_sizes, int n_in,
                              void* d_out, int out_size, void* d_ws,
                              size_t ws_size, hipStream_t stream) {
  const float* x = (const float*)d_in[0];
  const float* w1 = (const float*)d_in[1];
  const float* w2 = (const float*)d_in[2];
  char* ws = (char*)d_ws;
  float2* tab = (float2*)(ws + TAB_B);
  u16* qbf = (u16*)(ws + QBF_B);
  u16* kbf = (u16*)(ws + KBF_B);
  u16* vtbf = (u16*)(ws + VTB_B);
  u16* w2h = (u16*)(ws + W2H_B);
  u16* xbf = (u16*)(ws + XBF_B);
  u16* w1bf = (u16*)(ws + W1BF_B);
  u16* o16 = (u16*)(ws + O16_B);
  float* out = (float*)d_out;

  prep_kernel<<<dim3(2304), dim3(256), 0, stream>>>(x, w1, w2, tab, xbf, w1bf,
                                                    w2h);
  gemm_bt<0><<<dim3(32 * 24), dim3(256), 0, stream>>>(
      xbf, w1bf, 24, 16, tab, qbf, kbf, vtbf, nullptr);
  attn_mfma<<<dim3(512), dim3(256), 0, stream>>>(qbf, kbf, vtbf, o16);
  gemm_bt<1><<<dim3(32 * 8), dim3(256), 0, stream>>>(
      o16, w2h, 8, 16, nullptr, nullptr, nullptr, nullptr, out);
}